// Round 1
// baseline (813.815 us; speedup 1.0000x reference)
//
#include <hip/hip_runtime.h>
#include <hip/hip_bf16.h>

// Router MLP: X[16384,2048] @ W1[2048,1024] -> relu -> @ W2[1024,8] -> softmax -> top2
// Outputs (flat f32): logits[16384*8] | weights[16384*2] | indices-as-float[16384*2]

#define HDIM 2048
#define HM 1024
#define NROWS 16384
#define NE 8

#define BM 128
#define BN 128
#define BK 16
#define TM 8
#define TN 8

__global__ __launch_bounds__(256) void router_gemm1(
    const float* __restrict__ X, const float* __restrict__ W1,
    const float* __restrict__ b1, const float* __restrict__ W2,
    float* __restrict__ pl) {
  const int bid = blockIdx.x;
  const int rb = bid >> 3;  // row block 0..127
  const int nb = bid & 7;   // col chunk 0..7
  const int t = threadIdx.x;
  const int tcol = t & 15;
  const int trow = t >> 4;

  __shared__ float As[BK][BM + 4];    // k-major (transposed): As[k][row]
  __shared__ float Bs[BK][BN + 4];    // Bs[k][col]
  __shared__ float W2s[BN][NE + 1];   // +1 pad breaks 16-way bank conflict

  // stage this col-chunk of W2 (128x8)
  for (int i = t; i < BN * NE; i += 256) {
    int c = i >> 3, e = i & 7;
    W2s[c][e] = W2[(size_t)(nb * BN + c) * NE + e];
  }

  float acc[TM][TN];
#pragma unroll
  for (int i = 0; i < TM; ++i)
#pragma unroll
    for (int j = 0; j < TN; ++j) acc[i][j] = 0.f;

  const float* Xb = X + (size_t)rb * BM * HDIM;
  const float* W1b = W1 + (size_t)nb * BN;

  for (int kt = 0; kt < HDIM; kt += BK) {
    __syncthreads();  // previous iter's LDS reads done before overwrite
#pragma unroll
    for (int u = 0; u < 2; ++u) {
      int idx = t + u * 256;          // 0..511
      int row = idx >> 2;             // 0..127
      int k4 = (idx & 3) << 2;        // 0,4,8,12
      float4 v = *(const float4*)(Xb + (size_t)row * HDIM + kt + k4);
      As[k4 + 0][row] = v.x;
      As[k4 + 1][row] = v.y;
      As[k4 + 2][row] = v.z;
      As[k4 + 3][row] = v.w;
    }
#pragma unroll
    for (int u = 0; u < 2; ++u) {
      int idx = t + u * 256;
      int kr = idx >> 5;              // 0..15
      int c4 = (idx & 31) << 2;       // 0..124
      *(float4*)&Bs[kr][c4] =
          *(const float4*)(W1b + (size_t)(kt + kr) * HM + c4);
    }
    __syncthreads();
#pragma unroll
    for (int k = 0; k < BK; ++k) {
      float4 a0 = *(const float4*)&As[k][trow * TM];
      float4 a1 = *(const float4*)&As[k][trow * TM + 4];
      float4 bv0 = *(const float4*)&Bs[k][tcol * TN];
      float4 bv1 = *(const float4*)&Bs[k][tcol * TN + 4];
      float a[TM] = {a0.x, a0.y, a0.z, a0.w, a1.x, a1.y, a1.z, a1.w};
      float b[TN] = {bv0.x, bv0.y, bv0.z, bv0.w, bv1.x, bv1.y, bv1.z, bv1.w};
#pragma unroll
      for (int i = 0; i < TM; ++i)
#pragma unroll
        for (int j = 0; j < TN; ++j) acc[i][j] = fmaf(a[i], b[j], acc[i][j]);
    }
  }

  // epilogue: relu(acc + b1) @ W2-chunk -> partial logits, reduce over tcol lanes
  float bias[TN];
#pragma unroll
  for (int j = 0; j < TN; ++j) bias[j] = b1[nb * BN + tcol * TN + j];

#pragma unroll
  for (int i = 0; i < TM; ++i) {
    float plr[NE];
#pragma unroll
    for (int e = 0; e < NE; ++e) plr[e] = 0.f;
#pragma unroll
    for (int j = 0; j < TN; ++j) {
      float h = acc[i][j] + bias[j];
      h = fmaxf(h, 0.f);
#pragma unroll
      for (int e = 0; e < NE; ++e)
        plr[e] = fmaf(h, W2s[tcol * TN + j][e], plr[e]);
    }
    // reduce across the 16 tcol lanes (contiguous lane groups within the wave)
#pragma unroll
    for (int m = 1; m < 16; m <<= 1)
#pragma unroll
      for (int e = 0; e < NE; ++e) plr[e] += __shfl_xor(plr[e], m, 64);
    if (tcol == 0) {
      int row = rb * BM + trow * TM + i;
      float* dst = pl + ((size_t)nb * NROWS + row) * NE;
#pragma unroll
      for (int e = 0; e < NE; ++e) dst[e] = plr[e];
    }
  }
}

__global__ __launch_bounds__(256) void router_finalize(
    const float* __restrict__ pl, const float* __restrict__ b2,
    float* __restrict__ out) {
  int row = blockIdx.x * 256 + threadIdx.x;
  if (row >= NROWS) return;
  float l[NE];
#pragma unroll
  for (int e = 0; e < NE; ++e) l[e] = b2[e];
  for (int nb = 0; nb < 8; ++nb) {
    const float* src = pl + ((size_t)nb * NROWS + row) * NE;
#pragma unroll
    for (int e = 0; e < NE; ++e) l[e] += src[e];
  }
#pragma unroll
  for (int e = 0; e < NE; ++e) out[(size_t)row * NE + e] = l[e];

  float m = l[0];
#pragma unroll
  for (int e = 1; e < NE; ++e) m = fmaxf(m, l[e]);
  float p[NE], s = 0.f;
#pragma unroll
  for (int e = 0; e < NE; ++e) {
    p[e] = expf(l[e] - m);
    s += p[e];
  }
  float inv = 1.f / s;

  // top-2, strict > => lowest index wins ties (matches lax.top_k)
  float v0 = -1.f, v1 = -1.f;
  int i0 = 0, i1 = 0;
#pragma unroll
  for (int e = 0; e < NE; ++e) {
    float pe = p[e];
    if (pe > v0) {
      v1 = v0; i1 = i0;
      v0 = pe; i0 = e;
    } else if (pe > v1) {
      v1 = pe; i1 = e;
    }
  }
  size_t wbase = (size_t)NROWS * NE + (size_t)row * 2;
  out[wbase] = v0 * inv;
  out[wbase + 1] = v1 * inv;
  size_t ibase = (size_t)NROWS * NE + (size_t)NROWS * 2 + (size_t)row * 2;
  out[ibase] = (float)i0;
  out[ibase + 1] = (float)i1;
}

extern "C" void kernel_launch(void* const* d_in, const int* in_sizes, int n_in,
                              void* d_out, int out_size, void* d_ws,
                              size_t ws_size, hipStream_t stream) {
  const float* X = (const float*)d_in[0];
  const float* W1 = (const float*)d_in[1];
  const float* b1 = (const float*)d_in[2];
  const float* W2 = (const float*)d_in[3];
  const float* b2 = (const float*)d_in[4];
  float* out = (float*)d_out;
  float* pl = (float*)d_ws;  // 8 * 16384 * 8 floats = 4 MB partial logits

  hipLaunchKernelGGL(router_gemm1, dim3(1024), dim3(256), 0, stream, X, W1, b1,
                     W2, pl);
  hipLaunchKernelGGL(router_finalize, dim3(NROWS / 256), dim3(256), 0, stream,
                     pl, b2, out);
}

// Round 2
// 264.354 us; speedup vs baseline: 3.0785x; 3.0785x over previous
//
#include <hip/hip_runtime.h>
#include <hip/hip_bf16.h>

// Router MLP: X[16384,2048] @ W1[2048,1024] -> relu -> @ W2[1024,8] -> softmax -> top2
// f16 split-precision MFMA path: X = Xh + Xl, W1 = Wh + Wl (f16 hi/lo),
// X@W1 ~= Xh@Wh + Xh@Wl + Xl@Wh  (residual ~2^-24 relative -> fp32-class accuracy)
// Outputs (flat f32): logits[16384*8] | weights[16384*2] | indices-as-float[16384*2]

#define HDIM 2048
#define HM 1024
#define NROWS 16384
#define NE 8

typedef _Float16 f16;
typedef f16 f16x8 __attribute__((ext_vector_type(8)));
typedef float f32x4 __attribute__((ext_vector_type(4)));

// ---------------- prep: W1 [2048][1024] f32 -> W1T hi/lo [1024][2048] f16 ----
__global__ __launch_bounds__(256) void split_w1t(const float* __restrict__ W1,
                                                 f16* __restrict__ Th,
                                                 f16* __restrict__ Tl) {
  __shared__ f16 sh[64][72];
  __shared__ f16 sl[64][72];
  const int t = threadIdx.x;
  const int k0 = blockIdx.x * 64;
  const int n0 = blockIdx.y * 64;
  {
    const int r = t >> 2;            // 0..63 (k within tile)
    const int cb = (t & 3) * 16;     // 0..48 (n within tile)
    const float* src = W1 + (size_t)(k0 + r) * HM + n0 + cb;
    float xs[16];
#pragma unroll
    for (int u = 0; u < 4; ++u) {
      float4 v = *(const float4*)(src + u * 4);
      xs[u * 4 + 0] = v.x; xs[u * 4 + 1] = v.y;
      xs[u * 4 + 2] = v.z; xs[u * 4 + 3] = v.w;
    }
#pragma unroll
    for (int i = 0; i < 16; ++i) {
      f16 h = (f16)xs[i];
      sh[r][cb + i] = h;
      sl[r][cb + i] = (f16)(xs[i] - (float)h);
    }
  }
  __syncthreads();
  {
    const int n = t >> 2;            // 0..63 (n within tile)
    const int kc = (t & 3) * 16;     // 0..48 (k within tile)
    f16x8 oh0, oh1, ol0, ol1;
#pragma unroll
    for (int i = 0; i < 8; ++i) {
      oh0[i] = sh[kc + i][n];      ol0[i] = sl[kc + i][n];
      oh1[i] = sh[kc + 8 + i][n];  ol1[i] = sl[kc + 8 + i][n];
    }
    size_t base = (size_t)(n0 + n) * HDIM + k0 + kc;
    *(f16x8*)(Th + base) = oh0;  *(f16x8*)(Th + base + 8) = oh1;
    *(f16x8*)(Tl + base) = ol0;  *(f16x8*)(Tl + base + 8) = ol1;
  }
}

// ---------------- main: split-f16 MFMA GEMM + fused W2 epilogue --------------
// grid: (M/128) * (N/128) = 128*8 blocks; 256 threads = 4 waves (2x2), 64x64/wave
__global__ __launch_bounds__(256) void router_mfma(
    const float* __restrict__ X, const f16* __restrict__ W1Th,
    const f16* __restrict__ W1Tl, const float* __restrict__ b1,
    const float* __restrict__ W2, float* __restrict__ pl) {
  const int bid = blockIdx.x;
  const int rb = bid >> 3;  // row block 0..127
  const int nb = bid & 7;   // col block 0..7
  const int t = threadIdx.x;
  const int lane = t & 63;
  const int wave = t >> 6;
  const int wm = wave >> 1, wn = wave & 1;
  const int lane15 = lane & 15;
  const int lgrp = lane >> 4;  // 0..3

  __shared__ f16 Ah[128][40];
  __shared__ f16 Al[128][40];
  __shared__ f16 Bh[128][40];
  __shared__ f16 Bl[128][40];
  __shared__ float W2s[128][NE];

  for (int i = t; i < 128 * NE; i += 256) {
    int c = i >> 3, e = i & 7;
    W2s[c][e] = W2[(size_t)(nb * 128 + c) * NE + e];
  }

  f32x4 acc[4][4];
#pragma unroll
  for (int i = 0; i < 4; ++i)
#pragma unroll
    for (int j = 0; j < 4; ++j) acc[i][j] = (f32x4){0.f, 0.f, 0.f, 0.f};

  const int srow = t >> 1;          // 0..127 staging row
  const int skb = (t & 1) * 16;     // 0 or 16
  const float* Xrow = X + (size_t)(rb * 128 + srow) * HDIM + skb;
  const f16* Brh = W1Th + (size_t)(nb * 128 + srow) * HDIM + skb;
  const f16* Brl = W1Tl + (size_t)(nb * 128 + srow) * HDIM + skb;

#pragma unroll 1
  for (int kt = 0; kt < HDIM; kt += 32) {
    __syncthreads();
    // stage A (convert f32 -> f16 hi/lo)
    {
      const float4* src = (const float4*)(Xrow + kt);
      float xs[16];
#pragma unroll
      for (int u = 0; u < 4; ++u) {
        float4 v = src[u];
        xs[u * 4 + 0] = v.x; xs[u * 4 + 1] = v.y;
        xs[u * 4 + 2] = v.z; xs[u * 4 + 3] = v.w;
      }
      f16x8 h0, h1, l0, l1;
#pragma unroll
      for (int i = 0; i < 8; ++i) {
        f16 h = (f16)xs[i];
        h0[i] = h; l0[i] = (f16)(xs[i] - (float)h);
        f16 g = (f16)xs[8 + i];
        h1[i] = g; l1[i] = (f16)(xs[8 + i] - (float)g);
      }
      *(f16x8*)&Ah[srow][skb] = h0; *(f16x8*)&Ah[srow][skb + 8] = h1;
      *(f16x8*)&Al[srow][skb] = l0; *(f16x8*)&Al[srow][skb + 8] = l1;
    }
    // stage B (already f16 hi/lo in ws)
    {
      const f16x8* bh = (const f16x8*)(Brh + kt);
      const f16x8* bl = (const f16x8*)(Brl + kt);
      *(f16x8*)&Bh[srow][skb] = bh[0]; *(f16x8*)&Bh[srow][skb + 8] = bh[1];
      *(f16x8*)&Bl[srow][skb] = bl[0]; *(f16x8*)&Bl[srow][skb + 8] = bl[1];
    }
    __syncthreads();

    f16x8 ah[4], al[4], bh[4], bl[4];
#pragma unroll
    for (int mi = 0; mi < 4; ++mi) {
      int r = wm * 64 + mi * 16 + lane15;
      ah[mi] = *(const f16x8*)&Ah[r][lgrp * 8];
      al[mi] = *(const f16x8*)&Al[r][lgrp * 8];
    }
#pragma unroll
    for (int ni = 0; ni < 4; ++ni) {
      int c = wn * 64 + ni * 16 + lane15;
      bh[ni] = *(const f16x8*)&Bh[c][lgrp * 8];
      bl[ni] = *(const f16x8*)&Bl[c][lgrp * 8];
    }
#pragma unroll
    for (int mi = 0; mi < 4; ++mi)
#pragma unroll
      for (int ni = 0; ni < 4; ++ni) {
        acc[mi][ni] = __builtin_amdgcn_mfma_f32_16x16x32_f16(
            ah[mi], bh[ni], acc[mi][ni], 0, 0, 0);
        acc[mi][ni] = __builtin_amdgcn_mfma_f32_16x16x32_f16(
            ah[mi], bl[ni], acc[mi][ni], 0, 0, 0);
        acc[mi][ni] = __builtin_amdgcn_mfma_f32_16x16x32_f16(
            al[mi], bh[ni], acc[mi][ni], 0, 0, 0);
      }
  }

  __syncthreads();  // all LDS frag reads done; Ah region reused as reduce buf
  float* red = (float*)&Ah[0][0];  // red[2][128][8]

  float bvals[4];
#pragma unroll
  for (int ni = 0; ni < 4; ++ni)
    bvals[ni] = b1[nb * 128 + wn * 64 + ni * 16 + lane15];

#pragma unroll
  for (int mi = 0; mi < 4; ++mi) {
    float plr[4][NE];
#pragma unroll
    for (int j = 0; j < 4; ++j)
#pragma unroll
      for (int e = 0; e < NE; ++e) plr[j][e] = 0.f;
#pragma unroll
    for (int ni = 0; ni < 4; ++ni) {
      const float* w2r = W2s[wn * 64 + ni * 16 + lane15];
#pragma unroll
      for (int j = 0; j < 4; ++j) {
        float h = acc[mi][ni][j] + bvals[ni];
        h = fmaxf(h, 0.f);
#pragma unroll
        for (int e = 0; e < NE; ++e) plr[j][e] = fmaf(h, w2r[e], plr[j][e]);
      }
    }
#pragma unroll
    for (int m = 1; m < 16; m <<= 1)
#pragma unroll
      for (int j = 0; j < 4; ++j)
#pragma unroll
        for (int e = 0; e < NE; ++e)
          plr[j][e] += __shfl_xor(plr[j][e], m, 64);
    if (lane15 == 0) {
#pragma unroll
      for (int j = 0; j < 4; ++j) {
        int r = wm * 64 + mi * 16 + lgrp * 4 + j;
#pragma unroll
        for (int e = 0; e < NE; ++e)
          red[(size_t)wn * 128 * NE + r * NE + e] = plr[j][e];
      }
    }
  }
  __syncthreads();
  for (int i = t; i < 128 * NE; i += 256) {
    int r = i >> 3, e = i & 7;
    int row = rb * 128 + r;
    pl[((size_t)nb * NROWS + row) * NE + e] =
        red[r * NE + e] + red[128 * NE + r * NE + e];
  }
}

// ---------------- finalize: sum partials + bias2, softmax, top-2 -------------
__global__ __launch_bounds__(256) void router_finalize(
    const float* __restrict__ pl, const float* __restrict__ b2,
    float* __restrict__ out) {
  int row = blockIdx.x * 256 + threadIdx.x;
  if (row >= NROWS) return;
  float l[NE];
#pragma unroll
  for (int e = 0; e < NE; ++e) l[e] = b2[e];
  for (int nb = 0; nb < 8; ++nb) {
    const float* src = pl + ((size_t)nb * NROWS + row) * NE;
#pragma unroll
    for (int e = 0; e < NE; ++e) l[e] += src[e];
  }
#pragma unroll
  for (int e = 0; e < NE; ++e) out[(size_t)row * NE + e] = l[e];

  float m = l[0];
#pragma unroll
  for (int e = 1; e < NE; ++e) m = fmaxf(m, l[e]);
  float p[NE], s = 0.f;
#pragma unroll
  for (int e = 0; e < NE; ++e) {
    p[e] = expf(l[e] - m);
    s += p[e];
  }
  float inv = 1.f / s;

  float v0 = -1.f, v1 = -1.f;
  int i0 = 0, i1 = 0;
#pragma unroll
  for (int e = 0; e < NE; ++e) {
    float pe = p[e];
    if (pe > v0) {
      v1 = v0; i1 = i0;
      v0 = pe; i0 = e;
    } else if (pe > v1) {
      v1 = pe; i1 = e;
    }
  }
  size_t wbase = (size_t)NROWS * NE + (size_t)row * 2;
  out[wbase] = v0 * inv;
  out[wbase + 1] = v1 * inv;
  size_t ibase = (size_t)NROWS * NE + (size_t)NROWS * 2 + (size_t)row * 2;
  out[ibase] = (float)i0;
  out[ibase + 1] = (float)i1;
}

extern "C" void kernel_launch(void* const* d_in, const int* in_sizes, int n_in,
                              void* d_out, int out_size, void* d_ws,
                              size_t ws_size, hipStream_t stream) {
  const float* X = (const float*)d_in[0];
  const float* W1 = (const float*)d_in[1];
  const float* b1 = (const float*)d_in[2];
  const float* W2 = (const float*)d_in[3];
  const float* b2 = (const float*)d_in[4];
  float* out = (float*)d_out;

  // ws layout: pl 4 MB | W1Th 4 MB | W1Tl 4 MB  (needs 12 MB of ws)
  float* pl = (float*)d_ws;
  f16* W1Th = (f16*)((char*)d_ws + (size_t)4 * 1024 * 1024);
  f16* W1Tl = (f16*)((char*)d_ws + (size_t)8 * 1024 * 1024);

  hipLaunchKernelGGL(split_w1t, dim3(HDIM / 64, HM / 64), dim3(256), 0, stream,
                     W1, W1Th, W1Tl);
  hipLaunchKernelGGL(router_mfma, dim3(1024), dim3(256), 0, stream, X, W1Th,
                     W1Tl, b1, W2, pl);
  hipLaunchKernelGGL(router_finalize, dim3(NROWS / 256), dim3(256), 0, stream,
                     pl, b2, out);
}

// Round 3
// 244.384 us; speedup vs baseline: 3.3301x; 1.0817x over previous
//
#include <hip/hip_runtime.h>
#include <hip/hip_bf16.h>

// Router MLP: X[16384,2048] @ W1[2048,1024] -> relu -> @ W2[1024,8] -> softmax -> top2
// f16 split MFMA: X@W1 ~= Xh@Wh + Xh@Wl + Xl@Wh. A staged as raw f32 via
// global_load_lds, split in-register; B pre-split+pre-swizzled in ws.
// Pipeline: explicit dbuf, counted vmcnt(8), raw s_barriers (T3+T4 minimal).
// Outputs (flat f32): logits[16384*8] | weights[16384*2] | indices-as-float[16384*2]

#define HDIM 2048
#define HM 1024
#define NROWS 16384
#define NE 8
#define KSTEPS 64  // 2048 / 32

typedef _Float16 f16;
typedef f16 f16x8 __attribute__((ext_vector_type(8)));
typedef float f32x4 __attribute__((ext_vector_type(4)));

__device__ __forceinline__ void gload16(const void* g, void* l) {
  __builtin_amdgcn_global_load_lds(
      (const __attribute__((address_space(1))) void*)g,
      (__attribute__((address_space(3))) void*)l, 16, 0, 0);
}

// ---- prep: W1 [2048][1024] f32 -> W1s = swizzled LDS-image tiles ----------
// W1s[nb][ktidx] = 16KB image: row r (n = nb*128+r), 8 slots of 16B.
// LDS slot s' holds data-slot s = s'^(r&7); data: s<4 -> hi f16 of
// W1[kt+8s .. +8][n]; s>=4 -> lo f16 (x - (f16)x).
__global__ __launch_bounds__(128) void prep_w1(const float* __restrict__ W1,
                                               f16* __restrict__ W1s) {
  const int nb = blockIdx.x & 7;
  const int ktidx = blockIdx.x >> 3;
  const int r = threadIdx.x;  // 0..127
  const int n = nb * 128 + r;
  const int kt = ktidx * 32;
  f16 hi[32], lo[32];
#pragma unroll
  for (int kk = 0; kk < 32; ++kk) {
    float x = W1[(size_t)(kt + kk) * HM + n];
    f16 h = (f16)x;
    hi[kk] = h;
    lo[kk] = (f16)(x - (float)h);
  }
  f16* dst = W1s + (size_t)(nb * 64 + ktidx) * 8192 + r * 64;
#pragma unroll
  for (int sp = 0; sp < 8; ++sp) {
    int s = sp ^ (r & 7);
    f16x8 v;
#pragma unroll
    for (int j = 0; j < 8; ++j) v[j] = (s < 4) ? hi[8 * s + j] : lo[8 * (s - 4) + j];
    *(f16x8*)(dst + sp * 8) = v;
  }
}

// ---- main GEMM: 128x128 tile, BK=32, 4 waves (2x2), dbuf + counted vmcnt ---
__global__ __launch_bounds__(256) void router_mfma(
    const float* __restrict__ X, const f16* __restrict__ W1s,
    const float* __restrict__ b1, const float* __restrict__ W2,
    float* __restrict__ pl) {
  // XCD swizzle: 1024 wgs, 8 XCDs -> contiguous 128-wg chunk per XCD;
  // decode so same-rb (shared X panel) blocks cluster within an XCD.
  const int bid = blockIdx.x;
  const int wg = (bid & 7) * 128 + (bid >> 3);
  const int rb = wg >> 3;  // 0..127
  const int nb = wg & 7;   // 0..7

  const int t = threadIdx.x;
  const int lane = t & 63;
  const int wave = t >> 6;
  const int wm = wave >> 1, wn = wave & 1;
  const int lane15 = lane & 15;
  const int lgrp = lane >> 4;  // 0..3

  __shared__ char smem[2][32768];  // per buf: A f32 16KB | B f16 hi|lo 16KB

  // per-thread staging address precompute
  // A: thread t, issue i covers LDS image row ra = 32i + (t>>3), slot s' = t&7
  //    source data-slot sa = (t&7) ^ ((t>>3)&7)  (i-independent since 32i%8==0)
  const int sa = (t & 7) ^ ((t >> 3) & 7);
  size_t srcA[4];
#pragma unroll
  for (int i = 0; i < 4; ++i)
    srcA[i] = (size_t)(rb * 128 + 32 * i + (t >> 3)) * HDIM + 4 * sa;
  const char* W1sB = (const char*)W1s + (size_t)nb * 64 * 16384;

  auto STAGE = [&](int buf, int ktidx) {
    char* bA = &smem[buf][0];
    char* bB = &smem[buf][16384];
    const int ktf = ktidx * 32;
#pragma unroll
    for (int i = 0; i < 4; ++i)
      gload16(X + srcA[i] + ktf, bA + i * 4096 + wave * 1024);
#pragma unroll
    for (int i = 0; i < 4; ++i)
      gload16(W1sB + ((size_t)ktidx << 14) + i * 4096 + t * 16,
              bB + i * 4096 + wave * 1024);
  };

  f32x4 acc[4][4];
#pragma unroll
  for (int i = 0; i < 4; ++i)
#pragma unroll
    for (int j = 0; j < 4; ++j) acc[i][j] = (f32x4){0.f, 0.f, 0.f, 0.f};

  // prologue: fill both buffers, wait for buf0 only
  STAGE(0, 0);
  STAGE(1, 1);
  asm volatile("s_waitcnt vmcnt(8) lgkmcnt(0)" ::: "memory");
  __builtin_amdgcn_s_barrier();

  int cur = 0;
  for (int kti = 0; kti < KSTEPS; ++kti) {
    const float* ldsA = (const float*)&smem[cur][0];
    const f16* ldsB = (const f16*)&smem[cur][16384];

    f16x8 ah[4], al[4], bh[4], bl[4];
#pragma unroll
    for (int mi = 0; mi < 4; ++mi) {
      int r = wm * 64 + mi * 16 + lane15;
      int s0 = (2 * lgrp) ^ (r & 7);
      int s1 = (2 * lgrp + 1) ^ (r & 7);
      f32x4 va = *(const f32x4*)&ldsA[r * 32 + s0 * 4];
      f32x4 vb = *(const f32x4*)&ldsA[r * 32 + s1 * 4];
      float xs[8] = {va[0], va[1], va[2], va[3], vb[0], vb[1], vb[2], vb[3]};
#pragma unroll
      for (int j = 0; j < 8; ++j) {
        f16 h = (f16)xs[j];
        ah[mi][j] = h;
        al[mi][j] = (f16)(xs[j] - (float)h);
      }
    }
#pragma unroll
    for (int ni = 0; ni < 4; ++ni) {
      int c = wn * 64 + ni * 16 + lane15;
      int sh = lgrp ^ (c & 7);
      int sl = (4 + lgrp) ^ (c & 7);
      bh[ni] = *(const f16x8*)&ldsB[c * 64 + sh * 8];
      bl[ni] = *(const f16x8*)&ldsB[c * 64 + sl * 8];
    }
#pragma unroll
    for (int mi = 0; mi < 4; ++mi)
#pragma unroll
      for (int ni = 0; ni < 4; ++ni) {
        acc[mi][ni] = __builtin_amdgcn_mfma_f32_16x16x32_f16(
            ah[mi], bh[ni], acc[mi][ni], 0, 0, 0);
        acc[mi][ni] = __builtin_amdgcn_mfma_f32_16x16x32_f16(
            ah[mi], bl[ni], acc[mi][ni], 0, 0, 0);
        acc[mi][ni] = __builtin_amdgcn_mfma_f32_16x16x32_f16(
            al[mi], bh[ni], acc[mi][ni], 0, 0, 0);
      }

    if (kti == KSTEPS - 1) break;
    __builtin_amdgcn_sched_barrier(0);   // pin MFMAs + their lgkm waits above
    __builtin_amdgcn_s_barrier();        // #1: all waves done reading smem[cur]
    if (kti + 2 < KSTEPS) {
      STAGE(cur, kti + 2);
      asm volatile("s_waitcnt vmcnt(8)" ::: "memory");  // cur^1 landed
    } else {
      asm volatile("s_waitcnt vmcnt(0)" ::: "memory");  // tail: drain last tile
    }
    __builtin_amdgcn_s_barrier();        // #2: smem[cur^1] ready for all
    cur ^= 1;
  }

  // ---- fused epilogue: relu(acc+b1) @ W2 chunk, 16-lane reduce ----
  __syncthreads();
  float* red = (float*)&smem[0][0];  // [2][128][8] f32 = 8KB

  float bvals[4];
#pragma unroll
  for (int ni = 0; ni < 4; ++ni)
    bvals[ni] = b1[nb * 128 + wn * 64 + ni * 16 + lane15];
  float w2r[4][NE];
#pragma unroll
  for (int ni = 0; ni < 4; ++ni) {
    const float* src = W2 + (size_t)(nb * 128 + wn * 64 + ni * 16 + lane15) * NE;
#pragma unroll
    for (int e = 0; e < NE; ++e) w2r[ni][e] = src[e];
  }

#pragma unroll
  for (int mi = 0; mi < 4; ++mi) {
    float plr[4][NE];
#pragma unroll
    for (int j = 0; j < 4; ++j)
#pragma unroll
      for (int e = 0; e < NE; ++e) plr[j][e] = 0.f;
#pragma unroll
    for (int ni = 0; ni < 4; ++ni) {
#pragma unroll
      for (int j = 0; j < 4; ++j) {
        float h = acc[mi][ni][j] + bvals[ni];
        h = fmaxf(h, 0.f);
#pragma unroll
        for (int e = 0; e < NE; ++e) plr[j][e] = fmaf(h, w2r[ni][e], plr[j][e]);
      }
    }
#pragma unroll
    for (int m = 1; m < 16; m <<= 1)
#pragma unroll
      for (int j = 0; j < 4; ++j)
#pragma unroll
        for (int e = 0; e < NE; ++e)
          plr[j][e] += __shfl_xor(plr[j][e], m, 64);
    if (lane15 == 0) {
#pragma unroll
      for (int j = 0; j < 4; ++j) {
        int r = wm * 64 + mi * 16 + lgrp * 4 + j;
#pragma unroll
        for (int e = 0; e < NE; ++e)
          red[(size_t)wn * 128 * NE + r * NE + e] = plr[j][e];
      }
    }
  }
  __syncthreads();
  for (int i = t; i < 128 * NE; i += 256) {
    int r = i >> 3, e = i & 7;
    int row = rb * 128 + r;
    pl[((size_t)nb * NROWS + row) * NE + e] =
        red[r * NE + e] + red[128 * NE + r * NE + e];
  }
}

// ---- finalize: sum partials + b2, softmax, top-2 ----------------------------
__global__ __launch_bounds__(256) void router_finalize(
    const float* __restrict__ pl, const float* __restrict__ b2,
    float* __restrict__ out) {
  int row = blockIdx.x * 256 + threadIdx.x;
  if (row >= NROWS) return;
  float l[NE];
#pragma unroll
  for (int e = 0; e < NE; ++e) l[e] = b2[e];
  for (int nb = 0; nb < 8; ++nb) {
    const float* src = pl + ((size_t)nb * NROWS + row) * NE;
#pragma unroll
    for (int e = 0; e < NE; ++e) l[e] += src[e];
  }
#pragma unroll
  for (int e = 0; e < NE; ++e) out[(size_t)row * NE + e] = l[e];

  float m = l[0];
#pragma unroll
  for (int e = 1; e < NE; ++e) m = fmaxf(m, l[e]);
  float p[NE], s = 0.f;
#pragma unroll
  for (int e = 0; e < NE; ++e) {
    p[e] = expf(l[e] - m);
    s += p[e];
  }
  float inv = 1.f / s;

  float v0 = -1.f, v1 = -1.f;
  int i0 = 0, i1 = 0;
#pragma unroll
  for (int e = 0; e < NE; ++e) {
    float pe = p[e];
    if (pe > v0) {
      v1 = v0; i1 = i0;
      v0 = pe; i0 = e;
    } else if (pe > v1) {
      v1 = pe; i1 = e;
    }
  }
  size_t wbase = (size_t)NROWS * NE + (size_t)row * 2;
  out[wbase] = v0 * inv;
  out[wbase + 1] = v1 * inv;
  size_t ibase = (size_t)NROWS * NE + (size_t)NROWS * 2 + (size_t)row * 2;
  out[ibase] = (float)i0;
  out[ibase + 1] = (float)i1;
}

extern "C" void kernel_launch(void* const* d_in, const int* in_sizes, int n_in,
                              void* d_out, int out_size, void* d_ws,
                              size_t ws_size, hipStream_t stream) {
  const float* X = (const float*)d_in[0];
  const float* W1 = (const float*)d_in[1];
  const float* b1 = (const float*)d_in[2];
  const float* W2 = (const float*)d_in[3];
  const float* b2 = (const float*)d_in[4];
  float* out = (float*)d_out;

  // ws: pl 4MB | W1s 8MB (swizzled LDS-image tiles)
  float* pl = (float*)d_ws;
  f16* W1s = (f16*)((char*)d_ws + (size_t)4 * 1024 * 1024);

  hipLaunchKernelGGL(prep_w1, dim3(512), dim3(128), 0, stream, W1, W1s);
  hipLaunchKernelGGL(router_mfma, dim3(1024), dim3(256), 0, stream, X, W1s, b1,
                     W2, pl);
  hipLaunchKernelGGL(router_finalize, dim3(NROWS / 256), dim3(256), 0, stream,
                     pl, b2, out);
}

// Round 5
// 213.503 us; speedup vs baseline: 3.8117x; 1.1446x over previous
//
#include <hip/hip_runtime.h>
#include <hip/hip_bf16.h>

// Router MLP: X[16384,2048] @ W1[2048,1024] -> relu -> @ W2[1024,8] -> softmax -> top2
// f16 split MFMA: X@W1 ~= Xh@Wh + Xh@Wl + Xl@Wh.
// 256x256x32 tile, 8 waves, 128KiB dynamic LDS dbuf, counted vmcnt(8),
// A staged raw f32 via global_load_lds + in-register cvt_pkrtz split,
// B pre-split+pre-swizzled (W1s image) in ws.
// Outputs (flat f32): logits[16384*8] | weights[16384*2] | indices-as-float[16384*2]

#define HDIM 2048
#define HM 1024
#define NROWS 16384
#define NE 8
#define KSTEPS 64  // 2048 / 32

typedef _Float16 f16;
typedef f16 f16x8 __attribute__((ext_vector_type(8)));
typedef __fp16 h16x2 __attribute__((ext_vector_type(2)));
typedef float f32x4 __attribute__((ext_vector_type(4)));

union frag8 {
  f16x8 v;
  h16x2 p[4];
};

__device__ __forceinline__ void gload16(const void* g, void* l) {
  __builtin_amdgcn_global_load_lds(
      (const __attribute__((address_space(1))) void*)g,
      (__attribute__((address_space(3))) void*)l, 16, 0, 0);
}

// ---- prep: W1 [2048][1024] f32 -> W1s swizzled LDS-image tiles -------------
// W1s[nb][ktidx] = 32KB image: 256 rows (n = nb*256+r) x 8 slots of 16B.
// LDS slot sp holds data slot s = sp^(r&7); s<4: hi f16 of W1[kt+8s..+8][n],
// s>=4: lo f16 (x - (f16)x).
__global__ __launch_bounds__(256) void prep_w1(const float* __restrict__ W1,
                                               f16* __restrict__ W1s) {
  const int nb = blockIdx.x & 3;
  const int ktidx = blockIdx.x >> 2;
  const int r = threadIdx.x;  // 0..255
  const int n = nb * 256 + r;
  const int kt = ktidx * 32;
  f16 hi[32], lo[32];
#pragma unroll
  for (int kk = 0; kk < 32; ++kk) {
    float x = W1[(size_t)(kt + kk) * HM + n];
    f16 h = (f16)x;
    hi[kk] = h;
    lo[kk] = (f16)(x - (float)h);
  }
  f16* dst = W1s + (size_t)(nb * 64 + ktidx) * 16384 + r * 64;
#pragma unroll
  for (int sp = 0; sp < 8; ++sp) {
    int s = sp ^ (r & 7);
    f16x8 v;
#pragma unroll
    for (int j = 0; j < 8; ++j)
      v[j] = (s < 4) ? hi[8 * s + j] : lo[8 * (s - 4) + j];
    *(f16x8*)(dst + sp * 8) = v;
  }
}

// ---- main GEMM: 256x256 tile, BK=32, 8 waves (2x4), dbuf + counted vmcnt ---
__global__ __launch_bounds__(512, 2) void router_mfma(
    const float* __restrict__ X, const f16* __restrict__ W1s,
    const float* __restrict__ b1, const float* __restrict__ W2,
    float* __restrict__ pl) {
  // XCD swizzle: 256 wgs -> 32 contiguous per XCD; same-rb blocks cluster.
  const int bid = blockIdx.x;
  const int wg = (bid & 7) * 32 + (bid >> 3);
  const int rb = wg >> 2;  // 0..63
  const int nb = wg & 3;   // 0..3

  const int t = threadIdx.x;
  const int lane = t & 63;
  const int wave = t >> 6;       // 0..7
  const int wm = wave >> 2;      // 0..1  (128 rows each)
  const int wn = wave & 3;       // 0..3  (64 cols each)
  const int lane15 = lane & 15;
  const int lgrp = lane >> 4;    // 0..3

  extern __shared__ char smem[];  // [2][65536]: A f32 32KB | B f16 hi|lo 32KB

  // staging addresses: 512 threads x 4 issues cover 256 rows x 8 slots(16B)
  // issue i: row = 64i + (t>>3), LDS slot sp = t&7, data slot sa = sp^(row&7)
  const int sa = (t & 7) ^ ((t >> 3) & 7);
  const float* Xp[4];
#pragma unroll
  for (int i = 0; i < 4; ++i)
    Xp[i] = X + (size_t)(rb * 256 + 64 * i + (t >> 3)) * HDIM + 4 * sa;
  const char* W1sB = (const char*)W1s + (size_t)nb * 64 * 32768;

  auto STAGE = [&](int buf, int ktidx) {
    char* bA = smem + buf * 65536;
    char* bB = bA + 32768;
    const int ktf = ktidx * 32;
#pragma unroll
    for (int i = 0; i < 4; ++i)
      gload16(Xp[i] + ktf, bA + i * 8192 + t * 16);
#pragma unroll
    for (int i = 0; i < 4; ++i)
      gload16(W1sB + ((size_t)ktidx << 15) + i * 8192 + t * 16,
              bB + i * 8192 + t * 16);
  };

  f32x4 acc[8][4];
#pragma unroll
  for (int i = 0; i < 8; ++i)
#pragma unroll
    for (int j = 0; j < 4; ++j) acc[i][j] = (f32x4){0.f, 0.f, 0.f, 0.f};

  STAGE(0, 0);
  STAGE(1, 1);
  asm volatile("s_waitcnt vmcnt(8)" ::: "memory");
  __builtin_amdgcn_s_barrier();

  int cur = 0;
  for (int kti = 0; kti < KSTEPS; ++kti) {
    const char* ldsA = smem + cur * 65536;
    const f16* ldsB = (const f16*)(ldsA + 32768);

    // B fragments (pre-split hi/lo, swizzled)
    frag8 bh[4], bl[4];
#pragma unroll
    for (int ni = 0; ni < 4; ++ni) {
      int c = wn * 64 + ni * 16 + lane15;
      bh[ni].v = *(const f16x8*)&ldsB[c * 64 + ((lgrp ^ (c & 7)) << 3)];
      bl[ni].v = *(const f16x8*)&ldsB[c * 64 + (((4 + lgrp) ^ (c & 7)) << 3)];
    }

#pragma unroll
    for (int mi = 0; mi < 8; ++mi) {
      int r = wm * 128 + mi * 16 + lane15;
      const char* rowp = ldsA + r * 128;
      f32x4 va = *(const f32x4*)(rowp + ((((2 * lgrp) ^ (r & 7))) << 4));
      f32x4 vb = *(const f32x4*)(rowp + ((((2 * lgrp + 1) ^ (r & 7))) << 4));
      frag8 ah, al;
      h16x2 h0 = __builtin_amdgcn_cvt_pkrtz(va[0], va[1]);
      ah.p[0] = h0;
      al.p[0] = __builtin_amdgcn_cvt_pkrtz(va[0] - (float)h0[0],
                                           va[1] - (float)h0[1]);
      h16x2 h1 = __builtin_amdgcn_cvt_pkrtz(va[2], va[3]);
      ah.p[1] = h1;
      al.p[1] = __builtin_amdgcn_cvt_pkrtz(va[2] - (float)h1[0],
                                           va[3] - (float)h1[1]);
      h16x2 h2 = __builtin_amdgcn_cvt_pkrtz(vb[0], vb[1]);
      ah.p[2] = h2;
      al.p[2] = __builtin_amdgcn_cvt_pkrtz(vb[0] - (float)h2[0],
                                           vb[1] - (float)h2[1]);
      h16x2 h3 = __builtin_amdgcn_cvt_pkrtz(vb[2], vb[3]);
      ah.p[3] = h3;
      al.p[3] = __builtin_amdgcn_cvt_pkrtz(vb[2] - (float)h3[0],
                                           vb[3] - (float)h3[1]);
#pragma unroll
      for (int ni = 0; ni < 4; ++ni) {
        acc[mi][ni] = __builtin_amdgcn_mfma_f32_16x16x32_f16(
            ah.v, bh[ni].v, acc[mi][ni], 0, 0, 0);
        acc[mi][ni] = __builtin_amdgcn_mfma_f32_16x16x32_f16(
            ah.v, bl[ni].v, acc[mi][ni], 0, 0, 0);
        acc[mi][ni] = __builtin_amdgcn_mfma_f32_16x16x32_f16(
            al.v, bh[ni].v, acc[mi][ni], 0, 0, 0);
      }
    }

    if (kti == KSTEPS - 1) break;
    __builtin_amdgcn_sched_barrier(0);   // pin MFMAs + lgkm waits above
    __builtin_amdgcn_s_barrier();        // #1: all waves done reading smem[cur]
    if (kti + 2 < KSTEPS) {
      STAGE(cur, kti + 2);
      asm volatile("s_waitcnt vmcnt(8)" ::: "memory");  // cur^1 tile landed
    } else {
      asm volatile("s_waitcnt vmcnt(0)" ::: "memory");  // tail drain
    }
    __builtin_amdgcn_s_barrier();        // #2: smem[cur^1] ready
    cur ^= 1;
  }

  // ---- fused epilogue: relu(acc+b1) @ W2 chunk, 16-lane reduce ----
  __syncthreads();
  float* red = (float*)smem;  // [4][256][8] f32 = 32KB

  float bvals[4];
  float w2r[4][NE];
#pragma unroll
  for (int ni = 0; ni < 4; ++ni) {
    int c = nb * 256 + wn * 64 + ni * 16 + lane15;
    bvals[ni] = b1[c];
    const float* src = W2 + (size_t)c * NE;
#pragma unroll
    for (int e = 0; e < NE; ++e) w2r[ni][e] = src[e];
  }

#pragma unroll
  for (int mi = 0; mi < 8; ++mi) {
    float plr[4][NE];
#pragma unroll
    for (int j = 0; j < 4; ++j)
#pragma unroll
      for (int e = 0; e < NE; ++e) plr[j][e] = 0.f;
#pragma unroll
    for (int ni = 0; ni < 4; ++ni) {
#pragma unroll
      for (int j = 0; j < 4; ++j) {
        float h = acc[mi][ni][j] + bvals[ni];
        h = fmaxf(h, 0.f);
#pragma unroll
        for (int e = 0; e < NE; ++e) plr[j][e] = fmaf(h, w2r[ni][e], plr[j][e]);
      }
    }
#pragma unroll
    for (int m = 1; m < 16; m <<= 1)
#pragma unroll
      for (int j = 0; j < 4; ++j)
#pragma unroll
        for (int e = 0; e < NE; ++e)
          plr[j][e] += __shfl_xor(plr[j][e], m, 64);
    if (lane15 == 0) {
#pragma unroll
      for (int j = 0; j < 4; ++j) {
        int rr = wm * 128 + mi * 16 + lgrp * 4 + j;
#pragma unroll
        for (int e = 0; e < NE; ++e)
          red[(size_t)wn * 2048 + rr * NE + e] = plr[j][e];
      }
    }
  }
  __syncthreads();
  for (int i = t; i < 256 * NE; i += 512) {
    int r = i >> 3, e = i & 7;
    int row = rb * 256 + r;
    float s = red[i] + red[2048 + i] + red[4096 + i] + red[6144 + i];
    pl[((size_t)nb * NROWS + row) * NE + e] = s;
  }
}

// ---- finalize: sum partials + b2, softmax, top-2 ----------------------------
__global__ __launch_bounds__(256) void router_finalize(
    const float* __restrict__ pl, const float* __restrict__ b2,
    float* __restrict__ out) {
  int row = blockIdx.x * 256 + threadIdx.x;
  if (row >= NROWS) return;
  float l[NE];
#pragma unroll
  for (int e = 0; e < NE; ++e) l[e] = b2[e];
  for (int nb = 0; nb < 4; ++nb) {
    const float* src = pl + ((size_t)nb * NROWS + row) * NE;
#pragma unroll
    for (int e = 0; e < NE; ++e) l[e] += src[e];
  }
#pragma unroll
  for (int e = 0; e < NE; ++e) out[(size_t)row * NE + e] = l[e];

  float m = l[0];
#pragma unroll
  for (int e = 1; e < NE; ++e) m = fmaxf(m, l[e]);
  float p[NE], s = 0.f;
#pragma unroll
  for (int e = 0; e < NE; ++e) {
    p[e] = expf(l[e] - m);
    s += p[e];
  }
  float inv = 1.f / s;

  float v0 = -1.f, v1 = -1.f;
  int i0 = 0, i1 = 0;
#pragma unroll
  for (int e = 0; e < NE; ++e) {
    float pe = p[e];
    if (pe > v0) {
      v1 = v0; i1 = i0;
      v0 = pe; i0 = e;
    } else if (pe > v1) {
      v1 = pe; i1 = e;
    }
  }
  size_t wbase = (size_t)NROWS * NE + (size_t)row * 2;
  out[wbase] = v0 * inv;
  out[wbase + 1] = v1 * inv;
  size_t ibase = (size_t)NROWS * NE + (size_t)NROWS * 2 + (size_t)row * 2;
  out[ibase] = (float)i0;
  out[ibase + 1] = (float)i1;
}

extern "C" void kernel_launch(void* const* d_in, const int* in_sizes, int n_in,
                              void* d_out, int out_size, void* d_ws,
                              size_t ws_size, hipStream_t stream) {
  const float* X = (const float*)d_in[0];
  const float* W1 = (const float*)d_in[1];
  const float* b1 = (const float*)d_in[2];
  const float* W2 = (const float*)d_in[3];
  const float* b2 = (const float*)d_in[4];
  float* out = (float*)d_out;

  // ws: pl 2MB (at 0) | W1s 8MB (at +4MB)
  float* pl = (float*)d_ws;
  f16* W1s = (f16*)((char*)d_ws + (size_t)4 * 1024 * 1024);

  // allow 128 KiB dynamic LDS (non-stream runtime call; capture-safe)
  (void)hipFuncSetAttribute((const void*)router_mfma,
                            hipFuncAttributeMaxDynamicSharedMemorySize, 131072);

  hipLaunchKernelGGL(prep_w1, dim3(256), dim3(256), 0, stream, W1, W1s);
  hipLaunchKernelGGL(router_mfma, dim3(256), dim3(512), 131072, stream, X, W1s,
                     b1, W2, pl);
  hipLaunchKernelGGL(router_finalize, dim3(NROWS / 256), dim3(256), 0, stream,
                     pl, b2, out);
}

// Round 6
// 207.364 us; speedup vs baseline: 3.9246x; 1.0296x over previous
//
#include <hip/hip_runtime.h>
#include <hip/hip_bf16.h>

// Router MLP: X[16384,2048] @ W1[2048,1024] -> relu -> @ W2[1024,8] -> softmax -> top2
// f16 split MFMA: X@W1 ~= Xh@Wh + Xh@Wl + Xl@Wh.
// 256x256x32 tile, 8 waves, 128KiB LDS dbuf, counted vmcnt(8).
// R6: rolling one-ahead A-read pipeline inside the K-step (reads of mi+1
// issued before MFMAs of mi -> LDS latency hides under MFMA) + setprio(1)
// around MFMA clusters (T5; waves now phase-staggered so it can arbitrate).
// Outputs (flat f32): logits[16384*8] | weights[16384*2] | indices-as-float[16384*2]

#define HDIM 2048
#define HM 1024
#define NROWS 16384
#define NE 8
#define KSTEPS 64  // 2048 / 32

typedef _Float16 f16;
typedef f16 f16x8 __attribute__((ext_vector_type(8)));
typedef __fp16 h16x2 __attribute__((ext_vector_type(2)));
typedef float f32x4 __attribute__((ext_vector_type(4)));

union frag8 {
  f16x8 v;
  h16x2 p[4];
};

__device__ __forceinline__ void gload16(const void* g, void* l) {
  __builtin_amdgcn_global_load_lds(
      (const __attribute__((address_space(1))) void*)g,
      (__attribute__((address_space(3))) void*)l, 16, 0, 0);
}

// ---- prep: W1 [2048][1024] f32 -> W1s swizzled LDS-image tiles -------------
// W1s[nb][ktidx] = 32KB image: 256 rows (n = nb*256+r) x 8 slots of 16B.
// LDS slot sp holds data slot s = sp^(r&7); s<4: hi f16 of W1[kt+8s..+8][n],
// s>=4: lo f16 (x - (f16)x).
__global__ __launch_bounds__(256) void prep_w1(const float* __restrict__ W1,
                                               f16* __restrict__ W1s) {
  const int nb = blockIdx.x & 3;
  const int ktidx = blockIdx.x >> 2;
  const int r = threadIdx.x;  // 0..255
  const int n = nb * 256 + r;
  const int kt = ktidx * 32;
  f16 hi[32], lo[32];
#pragma unroll
  for (int kk = 0; kk < 32; ++kk) {
    float x = W1[(size_t)(kt + kk) * HM + n];
    f16 h = (f16)x;
    hi[kk] = h;
    lo[kk] = (f16)(x - (float)h);
  }
  f16* dst = W1s + (size_t)(nb * 64 + ktidx) * 16384 + r * 64;
#pragma unroll
  for (int sp = 0; sp < 8; ++sp) {
    int s = sp ^ (r & 7);
    f16x8 v;
#pragma unroll
    for (int j = 0; j < 8; ++j)
      v[j] = (s < 4) ? hi[8 * s + j] : lo[8 * (s - 4) + j];
    *(f16x8*)(dst + sp * 8) = v;
  }
}

// ---- main GEMM: 256x256 tile, BK=32, 8 waves (2x4), dbuf + counted vmcnt ---
__global__ __launch_bounds__(512, 2) void router_mfma(
    const float* __restrict__ X, const f16* __restrict__ W1s,
    const float* __restrict__ b1, const float* __restrict__ W2,
    float* __restrict__ pl) {
  // XCD swizzle: 256 wgs -> 32 contiguous per XCD; same-rb blocks cluster.
  const int bid = blockIdx.x;
  const int wg = (bid & 7) * 32 + (bid >> 3);
  const int rb = wg >> 2;  // 0..63
  const int nb = wg & 3;   // 0..3

  const int t = threadIdx.x;
  const int lane = t & 63;
  const int wave = t >> 6;       // 0..7
  const int wm = wave >> 2;      // 0..1  (128 rows each)
  const int wn = wave & 3;       // 0..3  (64 cols each)
  const int lane15 = lane & 15;
  const int lgrp = lane >> 4;    // 0..3

  extern __shared__ char smem[];  // [2][65536]: A f32 32KB | B f16 hi|lo 32KB

  // staging addresses: 512 threads x 4 issues cover 256 rows x 8 slots(16B)
  // issue i: row = 64i + (t>>3), LDS slot sp = t&7, data slot sa = sp^(row&7)
  const int sa = (t & 7) ^ ((t >> 3) & 7);
  const float* Xp[4];
#pragma unroll
  for (int i = 0; i < 4; ++i)
    Xp[i] = X + (size_t)(rb * 256 + 64 * i + (t >> 3)) * HDIM + 4 * sa;
  const char* W1sB = (const char*)W1s + (size_t)nb * 64 * 32768;

  auto STAGE = [&](int buf, int ktidx) {
    char* bA = smem + buf * 65536;
    char* bB = bA + 32768;
    const int ktf = ktidx * 32;
#pragma unroll
    for (int i = 0; i < 4; ++i)
      gload16(Xp[i] + ktf, bA + i * 8192 + t * 16);
#pragma unroll
    for (int i = 0; i < 4; ++i)
      gload16(W1sB + ((size_t)ktidx << 15) + i * 8192 + t * 16,
              bB + i * 8192 + t * 16);
  };

  f32x4 acc[8][4];
#pragma unroll
  for (int i = 0; i < 8; ++i)
#pragma unroll
    for (int j = 0; j < 4; ++j) acc[i][j] = (f32x4){0.f, 0.f, 0.f, 0.f};

  STAGE(0, 0);
  STAGE(1, 1);
  asm volatile("s_waitcnt vmcnt(8)" ::: "memory");
  __builtin_amdgcn_s_barrier();

  // A fragment read offsets (swizzled), per mi
  const int arow_base = wm * 128 + lane15;
  const int s0base = 2 * lgrp;

  int cur = 0;
  for (int kti = 0; kti < KSTEPS; ++kti) {
    const char* ldsA = smem + cur * 65536;
    const f16* ldsB = (const f16*)(ldsA + 32768);

    // B fragments for this K-tile (pre-split hi/lo, swizzled)
    frag8 bh[4], bl[4];
#pragma unroll
    for (int ni = 0; ni < 4; ++ni) {
      int c = wn * 64 + ni * 16 + lane15;
      bh[ni].v = *(const f16x8*)&ldsB[c * 64 + ((lgrp ^ (c & 7)) << 3)];
      bl[ni].v = *(const f16x8*)&ldsB[c * 64 + (((4 + lgrp) ^ (c & 7)) << 3)];
    }

    // rolling one-ahead A pipeline over mi
    f32x4 va, vb;
    {
      int r = arow_base;
      const char* rowp = ldsA + r * 128;
      va = *(const f32x4*)(rowp + (((s0base ^ (r & 7))) << 4));
      vb = *(const f32x4*)(rowp + ((((s0base + 1) ^ (r & 7))) << 4));
    }
#pragma unroll
    for (int mi = 0; mi < 8; ++mi) {
      f32x4 nva, nvb;
      if (mi < 7) {
        int r = arow_base + (mi + 1) * 16;
        const char* rowp = ldsA + r * 128;
        nva = *(const f32x4*)(rowp + (((s0base ^ (r & 7))) << 4));
        nvb = *(const f32x4*)(rowp + ((((s0base + 1) ^ (r & 7))) << 4));
      }
      frag8 ah, al;
      h16x2 h0 = __builtin_amdgcn_cvt_pkrtz(va[0], va[1]);
      ah.p[0] = h0;
      al.p[0] = __builtin_amdgcn_cvt_pkrtz(va[0] - (float)h0[0],
                                           va[1] - (float)h0[1]);
      h16x2 h1 = __builtin_amdgcn_cvt_pkrtz(va[2], va[3]);
      ah.p[1] = h1;
      al.p[1] = __builtin_amdgcn_cvt_pkrtz(va[2] - (float)h1[0],
                                           va[3] - (float)h1[1]);
      h16x2 h2 = __builtin_amdgcn_cvt_pkrtz(vb[0], vb[1]);
      ah.p[2] = h2;
      al.p[2] = __builtin_amdgcn_cvt_pkrtz(vb[0] - (float)h2[0],
                                           vb[1] - (float)h2[1]);
      h16x2 h3 = __builtin_amdgcn_cvt_pkrtz(vb[2], vb[3]);
      ah.p[3] = h3;
      al.p[3] = __builtin_amdgcn_cvt_pkrtz(vb[2] - (float)h3[0],
                                           vb[3] - (float)h3[1]);
      __builtin_amdgcn_s_setprio(1);
#pragma unroll
      for (int ni = 0; ni < 4; ++ni) {
        acc[mi][ni] = __builtin_amdgcn_mfma_f32_16x16x32_f16(
            ah.v, bh[ni].v, acc[mi][ni], 0, 0, 0);
        acc[mi][ni] = __builtin_amdgcn_mfma_f32_16x16x32_f16(
            ah.v, bl[ni].v, acc[mi][ni], 0, 0, 0);
        acc[mi][ni] = __builtin_amdgcn_mfma_f32_16x16x32_f16(
            al.v, bh[ni].v, acc[mi][ni], 0, 0, 0);
      }
      __builtin_amdgcn_s_setprio(0);
      va = nva;
      vb = nvb;
    }

    if (kti == KSTEPS - 1) break;
    __builtin_amdgcn_sched_barrier(0);   // pin all LDS reads above this point
    __builtin_amdgcn_s_barrier();        // #1: all waves done reading smem[cur]
    if (kti + 2 < KSTEPS) {
      STAGE(cur, kti + 2);
      asm volatile("s_waitcnt vmcnt(8)" ::: "memory");  // tile kti+1 landed
    } else {
      asm volatile("s_waitcnt vmcnt(0)" ::: "memory");  // tail drain
    }
    __builtin_amdgcn_s_barrier();        // #2: smem[cur^1] ready
    cur ^= 1;
  }

  // ---- fused epilogue: relu(acc+b1) @ W2 chunk, 16-lane reduce ----
  __syncthreads();
  float* red = (float*)smem;  // [4][256][8] f32 = 32KB

  float bvals[4];
  float w2r[4][NE];
#pragma unroll
  for (int ni = 0; ni < 4; ++ni) {
    int c = nb * 256 + wn * 64 + ni * 16 + lane15;
    bvals[ni] = b1[c];
    const float* src = W2 + (size_t)c * NE;
#pragma unroll
    for (int e = 0; e < NE; ++e) w2r[ni][e] = src[e];
  }

#pragma unroll
  for (int mi = 0; mi < 8; ++mi) {
    float plr[4][NE];
#pragma unroll
    for (int j = 0; j < 4; ++j)
#pragma unroll
      for (int e = 0; e < NE; ++e) plr[j][e] = 0.f;
#pragma unroll
    for (int ni = 0; ni < 4; ++ni) {
#pragma unroll
      for (int j = 0; j < 4; ++j) {
        float h = acc[mi][ni][j] + bvals[ni];
        h = fmaxf(h, 0.f);
#pragma unroll
        for (int e = 0; e < NE; ++e) plr[j][e] = fmaf(h, w2r[ni][e], plr[j][e]);
      }
    }
#pragma unroll
    for (int m = 1; m < 16; m <<= 1)
#pragma unroll
      for (int j = 0; j < 4; ++j)
#pragma unroll
        for (int e = 0; e < NE; ++e)
          plr[j][e] += __shfl_xor(plr[j][e], m, 64);
    if (lane15 == 0) {
#pragma unroll
      for (int j = 0; j < 4; ++j) {
        int rr = wm * 128 + mi * 16 + lgrp * 4 + j;
#pragma unroll
        for (int e = 0; e < NE; ++e)
          red[(size_t)wn * 2048 + rr * NE + e] = plr[j][e];
      }
    }
  }
  __syncthreads();
  for (int i = t; i < 256 * NE; i += 512) {
    int r = i >> 3, e = i & 7;
    int row = rb * 256 + r;
    float s = red[i] + red[2048 + i] + red[4096 + i] + red[6144 + i];
    pl[((size_t)nb * NROWS + row) * NE + e] = s;
  }
}

// ---- finalize: sum partials + b2, softmax, top-2 ----------------------------
__global__ __launch_bounds__(256) void router_finalize(
    const float* __restrict__ pl, const float* __restrict__ b2,
    float* __restrict__ out) {
  int row = blockIdx.x * 256 + threadIdx.x;
  if (row >= NROWS) return;
  float l[NE];
#pragma unroll
  for (int e = 0; e < NE; ++e) l[e] = b2[e];
  for (int nb = 0; nb < 4; ++nb) {
    const float* src = pl + ((size_t)nb * NROWS + row) * NE;
#pragma unroll
    for (int e = 0; e < NE; ++e) l[e] += src[e];
  }
#pragma unroll
  for (int e = 0; e < NE; ++e) out[(size_t)row * NE + e] = l[e];

  float m = l[0];
#pragma unroll
  for (int e = 1; e < NE; ++e) m = fmaxf(m, l[e]);
  float p[NE], s = 0.f;
#pragma unroll
  for (int e = 0; e < NE; ++e) {
    p[e] = expf(l[e] - m);
    s += p[e];
  }
  float inv = 1.f / s;

  float v0 = -1.f, v1 = -1.f;
  int i0 = 0, i1 = 0;
#pragma unroll
  for (int e = 0; e < NE; ++e) {
    float pe = p[e];
    if (pe > v0) {
      v1 = v0; i1 = i0;
      v0 = pe; i0 = e;
    } else if (pe > v1) {
      v1 = pe; i1 = e;
    }
  }
  size_t wbase = (size_t)NROWS * NE + (size_t)row * 2;
  out[wbase] = v0 * inv;
  out[wbase + 1] = v1 * inv;
  size_t ibase = (size_t)NROWS * NE + (size_t)NROWS * 2 + (size_t)row * 2;
  out[ibase] = (float)i0;
  out[ibase + 1] = (float)i1;
}

extern "C" void kernel_launch(void* const* d_in, const int* in_sizes, int n_in,
                              void* d_out, int out_size, void* d_ws,
                              size_t ws_size, hipStream_t stream) {
  const float* X = (const float*)d_in[0];
  const float* W1 = (const float*)d_in[1];
  const float* b1 = (const float*)d_in[2];
  const float* W2 = (const float*)d_in[3];
  const float* b2 = (const float*)d_in[4];
  float* out = (float*)d_out;

  // ws: pl 2MB (at 0) | W1s 8MB (at +4MB)
  float* pl = (float*)d_ws;
  f16* W1s = (f16*)((char*)d_ws + (size_t)4 * 1024 * 1024);

  // allow 128 KiB dynamic LDS (non-stream runtime call; capture-safe)
  (void)hipFuncSetAttribute((const void*)router_mfma,
                            hipFuncAttributeMaxDynamicSharedMemorySize, 131072);

  hipLaunchKernelGGL(prep_w1, dim3(256), dim3(256), 0, stream, W1, W1s);
  hipLaunchKernelGGL(router_mfma, dim3(256), dim3(512), 131072, stream, X, W1s,
                     b1, W2, pl);
  hipLaunchKernelGGL(router_finalize, dim3(NROWS / 256), dim3(256), 0, stream,
                     pl, b2, out);
}